// Round 7
// baseline (201.861 us; speedup 1.0000x reference)
//
#include <hip/hip_runtime.h>
#include <stdint.h>

#define N_DET 8192
#define E_DIM 64

typedef float  f32x16  __attribute__((ext_vector_type(16)));
typedef float  f32x4   __attribute__((ext_vector_type(4)));
typedef short  short8v __attribute__((ext_vector_type(8)));
typedef unsigned short ushort_t;

__device__ __forceinline__ unsigned fmap(float x) {
    unsigned b = __float_as_uint(x);
    return (b & 0x80000000u) ? ~b : (b | 0x80000000u);
}
__device__ __forceinline__ unsigned long long umax64(unsigned long long a, unsigned long long b) {
    return a > b ? a : b;
}
__device__ __forceinline__ ushort_t f2bf(float x) {   // round-to-nearest-even bf16
    unsigned u = __float_as_uint(x);
    unsigned r = u + 0x7fffu + ((u >> 16) & 1u);
    return (ushort_t)(r >> 16);
}

// ---------------- K1: embed; emit f32 + bf16 hi/lo in MFMA-fragment-packed layout ----
// Packed index: g=row>>5, s=k>>4, half=(k>>3)&1, r=row&31, e=k&7
//   P[g*2048 + s*512 + half*256 + r*8 + e]
// => K2 lane l reads short8 at P + g*2048 + s*512 + l*8  (contiguous 1KB per wave-load)
__global__ __launch_bounds__(256) void k_embed(
    const float* __restrict__ dt, const float* __restrict__ dt1,
    const float* __restrict__ W1, const float* __restrict__ b1,
    const float* __restrict__ W2, const float* __restrict__ b2,
    float* __restrict__ ef, ushort_t* __restrict__ Phi, ushort_t* __restrict__ Plo)
{
    int wave = (blockIdx.x * 256 + threadIdx.x) >> 6;
    int lane = threadIdx.x & 63;
    if (wave >= 2 * N_DET) return;
    const float* src = (wave < N_DET) ? (dt + (size_t)wave * 4)
                                      : (dt1 + (size_t)(wave - N_DET) * 4);
    float x0 = src[0], x1 = src[1], x2 = src[2], x3 = src[3];
    float h = b1[lane];
    h = fmaf(x0, W1[lane],        h);
    h = fmaf(x1, W1[64  + lane],  h);
    h = fmaf(x2, W1[128 + lane],  h);
    h = fmaf(x3, W1[192 + lane],  h);
    h = fmaxf(h, 0.0f);
    float e = b2[lane];
    #pragma unroll
    for (int k = 0; k < 64; ++k) {
        float hk = __shfl(h, k, 64);
        e = fmaf(hk, W2[k * 64 + lane], e);
    }
    float s = e * e;
    #pragma unroll
    for (int m = 32; m >= 1; m >>= 1) s += __shfl_xor(s, m, 64);
    float n = sqrtf(s);
    n = fmaxf(n, 1e-12f);
    float v = e / n;
    ef[(size_t)wave * 64 + lane] = v;

    ushort_t h16 = f2bf(v);
    float hf = __uint_as_float(((unsigned)h16) << 16);
    int paddr = (wave >> 5) * 2048 + (lane >> 4) * 512 + ((lane >> 3) & 1) * 256
              + (wave & 31) * 8 + (lane & 7);
    Phi[paddr] = h16;
    Plo[paddr] = f2bf(v - hf);
}

// ---------------- K2: split-bf16 MFMA sim + per-64col top-2 candidates ----------------
// Block 128x128 (4 waves, each 64x64 = 2x2 tiles of 32x32). No barriers (per-wave LDS).
// sim = hi*hi' + hi*lo' + lo*hi'. Epilogue: chunked 32-row LDS transpose ->
// dwordx4 NT stores (1KB/instr) + parallel top-2 scan.
__global__ __launch_bounds__(256) void k_sim_mfma(
    const ushort_t* __restrict__ Phi, const ushort_t* __restrict__ Plo,
    float* __restrict__ sim, unsigned* __restrict__ candbuf)
{
    __shared__ float sm[4][32][65];   // 33 KB: per-wave 32-row transpose buffer
    const int tid  = threadIdx.x;
    const int l    = tid & 63;
    const int w    = tid >> 6;
    const int l31  = l & 31;
    const int half = l >> 5;

    // XCD-chunked swizzle: 4096 blocks, 8 XCDs -> each XCD owns contiguous tile-rows
    const int bid = blockIdx.x;
    const int swz = (bid & 7) * 512 + (bid >> 3);
    const int bx = swz & 63, by = swz >> 6;

    const int rowbase = by * 128 + (w >> 1) * 64;
    const int colbase = bx * 128 + (w & 1) * 64;

    const short8v* PhiV = (const short8v*)Phi;   // index in short8 units
    const short8v* PloV = (const short8v*)Plo;
    const int GA0 = ((rowbase >> 5)      ) * 256;
    const int GA1 = GA0 + 256;
    const int GB0 = (256 + (colbase >> 5)) * 256;   // B rows offset by N_DET -> +256 groups
    const int GB1 = GB0 + 256;

    f32x16 acc00 = {}; f32x16 acc01 = {}; f32x16 acc10 = {}; f32x16 acc11 = {};
    asm volatile("s_nop 1" : "+v"(acc00), "+v"(acc01), "+v"(acc10), "+v"(acc11));

    #pragma unroll
    for (int s = 0; s < 4; ++s) {
        const int o = s * 64 + l;
        short8v a0h = PhiV[GA0 + o];
        short8v a1h = PhiV[GA1 + o];
        short8v b0h = PhiV[GB0 + o];
        short8v b1h = PhiV[GB1 + o];
        short8v a0l = PloV[GA0 + o];
        short8v a1l = PloV[GA1 + o];
        short8v b0l = PloV[GB0 + o];
        short8v b1l = PloV[GB1 + o];
        // hi*hi
        asm volatile("v_mfma_f32_32x32x16_bf16 %0, %1, %2, %0" : "+v"(acc00) : "v"(a0h), "v"(b0h));
        asm volatile("v_mfma_f32_32x32x16_bf16 %0, %1, %2, %0" : "+v"(acc01) : "v"(a0h), "v"(b1h));
        asm volatile("v_mfma_f32_32x32x16_bf16 %0, %1, %2, %0" : "+v"(acc10) : "v"(a1h), "v"(b0h));
        asm volatile("v_mfma_f32_32x32x16_bf16 %0, %1, %2, %0" : "+v"(acc11) : "v"(a1h), "v"(b1h));
        // hi*lo
        asm volatile("v_mfma_f32_32x32x16_bf16 %0, %1, %2, %0" : "+v"(acc00) : "v"(a0h), "v"(b0l));
        asm volatile("v_mfma_f32_32x32x16_bf16 %0, %1, %2, %0" : "+v"(acc01) : "v"(a0h), "v"(b1l));
        asm volatile("v_mfma_f32_32x32x16_bf16 %0, %1, %2, %0" : "+v"(acc10) : "v"(a1h), "v"(b0l));
        asm volatile("v_mfma_f32_32x32x16_bf16 %0, %1, %2, %0" : "+v"(acc11) : "v"(a1h), "v"(b1l));
        // lo*hi
        asm volatile("v_mfma_f32_32x32x16_bf16 %0, %1, %2, %0" : "+v"(acc00) : "v"(a0l), "v"(b0h));
        asm volatile("v_mfma_f32_32x32x16_bf16 %0, %1, %2, %0" : "+v"(acc01) : "v"(a0l), "v"(b1h));
        asm volatile("v_mfma_f32_32x32x16_bf16 %0, %1, %2, %0" : "+v"(acc10) : "v"(a1l), "v"(b0h));
        asm volatile("v_mfma_f32_32x32x16_bf16 %0, %1, %2, %0" : "+v"(acc11) : "v"(a1l), "v"(b1h));
    }
    // MFMA -> VALU/DS read-of-dst hazard fence
    asm volatile("s_nop 7\n\ts_nop 7\n\ts_nop 7"
                 : "+v"(acc00), "+v"(acc01), "+v"(acc10), "+v"(acc11));

    const int cb = bx * 2 + (w & 1);          // 64-col block index, 0..127

    // two 32-row chunks: LDS transpose -> dwordx4 NT stores + parallel top-2 scan
    #pragma unroll
    for (int chunk = 0; chunk < 2; ++chunk) {
        // 1) acc -> LDS.  C/D layout: col = lane&31, row = (reg&3)+8*(reg>>2)+4*(lane>>5)
        #pragma unroll
        for (int reg = 0; reg < 16; ++reg) {
            const int rowloc = (reg & 3) + ((reg >> 2) << 3) + (half << 2);  // 0..31
            float v0 = chunk ? acc10[reg] : acc00[reg];
            float v1 = chunk ? acc11[reg] : acc01[reg];
            sm[w][rowloc][l31]      = v0;
            sm[w][rowloc][l31 + 32] = v1;
        }
        // (per-wave LDS: in-order DS, no barrier needed)

        // 2) read back float4 + 16B/lane NT store (1KB per instruction)
        #pragma unroll
        for (int i = 0; i < 8; ++i) {
            int f    = i * 64 + l;           // 0..511
            int row  = f >> 4;               // 0..31
            int slot = f & 15;               // float4 slot within 64 cols
            f32x4 v = *(const f32x4*)&sm[w][row][slot * 4];
            f32x4* sp = (f32x4*)(sim + (size_t)(rowbase + chunk * 32 + row) * N_DET
                                     + colbase) + slot;
            __builtin_nontemporal_store(v, sp);
        }

        // 3) top-2 scan: lane -> (row = l&31, col-half = l>>5), 32 cols each
        {
            const int srow = l31;
            const int cofs = half * 32;
            float m1 = -3.0e38f, m2 = -3.0e38f;
            int   i1 = 0, i2 = 0;
            #pragma unroll
            for (int q = 0; q < 8; ++q) {
                f32x4 v = *(const f32x4*)&sm[w][srow][cofs + q * 4];
                float vv[4] = {v.x, v.y, v.z, v.w};
                #pragma unroll
                for (int e = 0; e < 4; ++e) {
                    int c = cofs + q * 4 + e;
                    bool gt1 = vv[e] > m1;
                    bool gt2 = vv[e] > m2;
                    m2 = gt1 ? m1 : (gt2 ? vv[e] : m2);
                    i2 = gt1 ? i1 : (gt2 ? c : i2);
                    m1 = gt1 ? vv[e] : m1;
                    i1 = gt1 ? c : i1;
                }
            }
            // merge halves (partner lane^32 holds the other 32 cols).
            // For lanes<32: own cols < partner cols; strict-> keeps first occurrence.
            float bm1 = __shfl_xor(m1, 32, 64);
            float bm2 = __shfl_xor(m2, 32, 64);
            int   bi1 = __shfl_xor(i1, 32, 64);
            int   bi2 = __shfl_xor(i2, 32, 64);
            float M1, M2; int I1, I2;
            if (bm1 > m1) {
                M1 = bm1; I1 = bi1;
                bool t = bm2 > m1;
                M2 = t ? bm2 : m1; I2 = t ? bi2 : i1;
            } else {
                M1 = m1; I1 = i1;
                bool t = bm1 > m2;
                M2 = t ? bm1 : m2; I2 = t ? bi1 : i2;
            }
            if (l < 32) {
                int row = rowbase + chunk * 32 + srow;
                candbuf[(size_t)row * 128 + cb] =
                    ((unsigned)(colbase + I1) << 16) | (unsigned)(colbase + I2);
            }
        }
        // chunk1's LDS writes are ordered after chunk0's reads (in-order per-wave DS)
    }
}

// ---------------- K3: exact f32 rescue of candidates -> rowkey, fused claim --------
// One wave per row; 4 candidates per lane; dot order == rounds-2/3 fmaf chain.
__global__ __launch_bounds__(256) void k_rescue(
    const float* __restrict__ ef, const unsigned* __restrict__ candbuf,
    unsigned long long* __restrict__ rowkey, unsigned long long* __restrict__ winner,
    unsigned uthr)
{
    const int row = blockIdx.x * 4 + (threadIdx.x >> 6);
    const int l   = threadIdx.x & 63;
    const float* et1f = ef + (size_t)N_DET * 64;

    unsigned cw0 = candbuf[(size_t)row * 128 + l];
    unsigned cw1 = candbuf[(size_t)row * 128 + 64 + l];
    int cols[4] = { (int)(cw0 >> 16), (int)(cw0 & 0xffffu),
                    (int)(cw1 >> 16), (int)(cw1 & 0xffffu) };

    float4 q[16];
    const float4* qp = (const float4*)(ef + (size_t)row * 64);
    #pragma unroll
    for (int i = 0; i < 16; ++i) q[i] = qp[i];

    unsigned long long best = 0ull;
    #pragma unroll
    for (int c = 0; c < 4; ++c) {
        const float4* rp = (const float4*)(et1f + (size_t)cols[c] * 64);
        float d = 0.0f;
        #pragma unroll
        for (int i = 0; i < 16; ++i) {
            float4 v = rp[i];
            d = fmaf(q[i].x, v.x, d);
            d = fmaf(q[i].y, v.y, d);
            d = fmaf(q[i].z, v.z, d);
            d = fmaf(q[i].w, v.w, d);
        }
        unsigned long long k =
            ((unsigned long long)fmap(d) << 32) | (unsigned)(~cols[c]);
        best = umax64(best, k);
    }
    #pragma unroll
    for (int m = 1; m < 64; m <<= 1)
        best = umax64(best, __shfl_xor(best, m, 64));
    if (l == 0) {
        rowkey[row] = best;
        unsigned u = (unsigned)(best >> 32);
        if (u > uthr) {
            unsigned col = ~(unsigned)best;
            unsigned long long claim = ((unsigned long long)u << 32) | (~(unsigned)row);
            atomicMax(&winner[col], claim);
        }
    }
}

// ---------------- K0: zero winner ----------------
__global__ void k_init(unsigned long long* __restrict__ p) {
    p[blockIdx.x * 256 + threadIdx.x] = 0ull;
}

// ---------------- K4: resolve matches ----------------
__global__ void k_match(const unsigned long long* __restrict__ rowkey,
                        const unsigned long long* __restrict__ winner,
                        float* __restrict__ out, unsigned uthr) {
    int i = blockIdx.x * 256 + threadIdx.x;
    if (i >= N_DET) return;
    unsigned long long k = rowkey[i];
    unsigned u = (unsigned)(k >> 32);
    float m = -1.0f;
    if (u > uthr) {
        unsigned col = ~(unsigned)k;
        unsigned long long claim = ((unsigned long long)u << 32) | (~(unsigned)i);
        if (winner[col] == claim) m = (float)col;
    }
    out[i] = m;
}

extern "C" void kernel_launch(void* const* d_in, const int* in_sizes, int n_in,
                              void* d_out, int out_size, void* d_ws, size_t ws_size,
                              hipStream_t stream) {
    const float* dt  = (const float*)d_in[0];
    const float* dt1 = (const float*)d_in[1];
    const float* W1  = (const float*)d_in[2];
    const float* b1  = (const float*)d_in[3];
    const float* W2  = (const float*)d_in[4];
    const float* b2  = (const float*)d_in[5];

    float* out = (float*)d_out;            // [0:8192) matches (float), then sim row-major
    float* sim = out + N_DET;

    char* ws = (char*)d_ws;
    float*    ef      = (float*)ws;                                   // 2N*64 f32 = 4 MB
    ushort_t* Phi     = (ushort_t*)(ws + (4u << 20));                 // 2 MB packed
    ushort_t* Plo     = (ushort_t*)(ws + (6u << 20));                 // 2 MB packed
    unsigned* candbuf = (unsigned*)(ws + (8u << 20));                 // 8192*128 u32 = 4 MB
    unsigned long long* rowkey = (unsigned long long*)(ws + (12u << 20)); // 64 KB
    unsigned long long* winner = rowkey + N_DET;                          // 64 KB

    unsigned uthr;
    { union { float f; unsigned u; } c; c.f = 0.3f; uthr = c.u | 0x80000000u; }

    k_embed<<<(2 * N_DET) / 4, 256, 0, stream>>>(dt, dt1, W1, b1, W2, b2, ef, Phi, Plo);
    k_init<<<N_DET / 256, 256, 0, stream>>>(winner);

    k_sim_mfma<<<4096, 256, 0, stream>>>(Phi, Plo, sim, candbuf);

    k_rescue<<<N_DET / 4, 256, 0, stream>>>(ef, candbuf, rowkey, winner, uthr);
    k_match<<<N_DET / 256, 256, 0, stream>>>(rowkey, winner, out, uthr);
}

// Round 10
// 167.688 us; speedup vs baseline: 1.2038x; 1.2038x over previous
//
#include <hip/hip_runtime.h>
#include <stdint.h>

#define N_DET 8192
#define E_DIM 64

typedef float  f32x16  __attribute__((ext_vector_type(16)));
typedef float  f32x4   __attribute__((ext_vector_type(4)));
typedef short  short8v __attribute__((ext_vector_type(8)));
typedef unsigned long long u64;
typedef unsigned short ushort_t;

__device__ __forceinline__ unsigned fmap(float x) {
    unsigned b = __float_as_uint(x);
    return (b & 0x80000000u) ? ~b : (b | 0x80000000u);
}
__device__ __forceinline__ u64 umax64(u64 a, u64 b) { return a > b ? a : b; }
__device__ __forceinline__ ushort_t f2bf(float x) {   // round-to-nearest-even bf16
    unsigned u = __float_as_uint(x);
    unsigned r = u + 0x7fffu + ((u >> 16) & 1u);
    return (ushort_t)(r >> 16);
}

// ---------------- K1: embed; emit f32 + bf16 hi/lo in MFMA-fragment-packed layout ----
__global__ __launch_bounds__(256) void k_embed(
    const float* __restrict__ dt, const float* __restrict__ dt1,
    const float* __restrict__ W1, const float* __restrict__ b1,
    const float* __restrict__ W2, const float* __restrict__ b2,
    float* __restrict__ ef, ushort_t* __restrict__ Phi, ushort_t* __restrict__ Plo)
{
    int wave = (blockIdx.x * 256 + threadIdx.x) >> 6;
    int lane = threadIdx.x & 63;
    if (wave >= 2 * N_DET) return;
    const float* src = (wave < N_DET) ? (dt + (size_t)wave * 4)
                                      : (dt1 + (size_t)(wave - N_DET) * 4);
    float x0 = src[0], x1 = src[1], x2 = src[2], x3 = src[3];
    float h = b1[lane];
    h = fmaf(x0, W1[lane],        h);
    h = fmaf(x1, W1[64  + lane],  h);
    h = fmaf(x2, W1[128 + lane],  h);
    h = fmaf(x3, W1[192 + lane],  h);
    h = fmaxf(h, 0.0f);
    float e = b2[lane];
    #pragma unroll
    for (int k = 0; k < 64; ++k) {
        float hk = __shfl(h, k, 64);
        e = fmaf(hk, W2[k * 64 + lane], e);
    }
    float s = e * e;
    #pragma unroll
    for (int m = 32; m >= 1; m >>= 1) s += __shfl_xor(s, m, 64);
    float n = sqrtf(s);
    n = fmaxf(n, 1e-12f);
    float v = e / n;
    ef[(size_t)wave * 64 + lane] = v;

    ushort_t h16 = f2bf(v);
    float hf = __uint_as_float(((unsigned)h16) << 16);
    int paddr = (wave >> 5) * 2048 + (lane >> 4) * 512 + ((lane >> 3) & 1) * 256
              + (wave & 31) * 8 + (lane & 7);
    Phi[paddr] = h16;
    Plo[paddr] = f2bf(v - hf);
}

// ---------------- K2: split-bf16 MFMA sim + per-64col top-2 candidates ----------------
// Block 128x128 (4 waves, each 64x64 = 2x2 tiles of 32x32). No barriers (per-wave LDS).
// sim = hi*hi' + hi*lo' + lo*hi'.
__global__ __launch_bounds__(256) void k_sim_mfma(
    const ushort_t* __restrict__ Phi, const ushort_t* __restrict__ Plo,
    float* __restrict__ sim, unsigned* __restrict__ candbuf)
{
    __shared__ float sm[4][32][65];   // 33 KB: per-wave 32-row transpose buffer
    const int tid  = threadIdx.x;
    const int l    = tid & 63;
    const int w    = tid >> 6;
    const int l31  = l & 31;
    const int half = l >> 5;

    // XCD-chunked swizzle: 4096 blocks, 8 XCDs
    const int bid = blockIdx.x;
    const int swz = (bid & 7) * 512 + (bid >> 3);
    const int bx = swz & 63, by = swz >> 6;

    const int rowbase = by * 128 + (w >> 1) * 64;
    const int colbase = bx * 128 + (w & 1) * 64;

    const short8v* PhiV = (const short8v*)Phi;   // index in short8 units
    const short8v* PloV = (const short8v*)Plo;
    const int GA0 = ((rowbase >> 5)      ) * 256;
    const int GA1 = GA0 + 256;
    const int GB0 = (256 + (colbase >> 5)) * 256;   // B rows offset by N_DET
    const int GB1 = GB0 + 256;

    f32x16 acc00 = {}; f32x16 acc01 = {}; f32x16 acc10 = {}; f32x16 acc11 = {};
    asm volatile("s_nop 1" : "+v"(acc00), "+v"(acc01), "+v"(acc10), "+v"(acc11));

    #pragma unroll
    for (int s = 0; s < 4; ++s) {
        const int o = s * 64 + l;
        short8v a0h = PhiV[GA0 + o];
        short8v a1h = PhiV[GA1 + o];
        short8v b0h = PhiV[GB0 + o];
        short8v b1h = PhiV[GB1 + o];
        short8v a0l = PloV[GA0 + o];
        short8v a1l = PloV[GA1 + o];
        short8v b0l = PloV[GB0 + o];
        short8v b1l = PloV[GB1 + o];
        // hi*hi
        asm volatile("v_mfma_f32_32x32x16_bf16 %0, %1, %2, %0" : "+v"(acc00) : "v"(a0h), "v"(b0h));
        asm volatile("v_mfma_f32_32x32x16_bf16 %0, %1, %2, %0" : "+v"(acc01) : "v"(a0h), "v"(b1h));
        asm volatile("v_mfma_f32_32x32x16_bf16 %0, %1, %2, %0" : "+v"(acc10) : "v"(a1h), "v"(b0h));
        asm volatile("v_mfma_f32_32x32x16_bf16 %0, %1, %2, %0" : "+v"(acc11) : "v"(a1h), "v"(b1h));
        // hi*lo
        asm volatile("v_mfma_f32_32x32x16_bf16 %0, %1, %2, %0" : "+v"(acc00) : "v"(a0h), "v"(b0l));
        asm volatile("v_mfma_f32_32x32x16_bf16 %0, %1, %2, %0" : "+v"(acc01) : "v"(a0h), "v"(b1l));
        asm volatile("v_mfma_f32_32x32x16_bf16 %0, %1, %2, %0" : "+v"(acc10) : "v"(a1h), "v"(b0l));
        asm volatile("v_mfma_f32_32x32x16_bf16 %0, %1, %2, %0" : "+v"(acc11) : "v"(a1h), "v"(b1l));
        // lo*hi
        asm volatile("v_mfma_f32_32x32x16_bf16 %0, %1, %2, %0" : "+v"(acc00) : "v"(a0l), "v"(b0h));
        asm volatile("v_mfma_f32_32x32x16_bf16 %0, %1, %2, %0" : "+v"(acc01) : "v"(a0l), "v"(b1h));
        asm volatile("v_mfma_f32_32x32x16_bf16 %0, %1, %2, %0" : "+v"(acc10) : "v"(a1l), "v"(b0h));
        asm volatile("v_mfma_f32_32x32x16_bf16 %0, %1, %2, %0" : "+v"(acc11) : "v"(a1l), "v"(b1h));
    }
    // MFMA -> VALU/DS read-of-dst hazard fence
    asm volatile("s_nop 7\n\ts_nop 7\n\ts_nop 7"
                 : "+v"(acc00), "+v"(acc01), "+v"(acc10), "+v"(acc11));

    const int cb = bx * 2 + (w & 1);          // 64-col block index, 0..127

    // two 32-row chunks: LDS transpose -> dwordx4 NT stores + parallel top-2 scan
    #pragma unroll
    for (int chunk = 0; chunk < 2; ++chunk) {
        // 1) acc -> LDS.  C/D layout: col = lane&31, row = (reg&3)+8*(reg>>2)+4*(lane>>5)
        #pragma unroll
        for (int reg = 0; reg < 16; ++reg) {
            const int rowloc = (reg & 3) + ((reg >> 2) << 3) + (half << 2);  // 0..31
            float v0 = chunk ? acc10[reg] : acc00[reg];
            float v1 = chunk ? acc11[reg] : acc01[reg];
            sm[w][rowloc][l31]      = v0;
            sm[w][rowloc][l31 + 32] = v1;
        }
        // (per-wave LDS: in-order DS, no barrier needed)

        // 2) read back float4 + 16B/lane NT store (1KB per instruction)
        #pragma unroll
        for (int i = 0; i < 8; ++i) {
            int f    = i * 64 + l;           // 0..511
            int row  = f >> 4;               // 0..31
            int slot = f & 15;               // float4 slot within 64 cols
            f32x4 v = *(const f32x4*)&sm[w][row][slot * 4];
            f32x4* sp = (f32x4*)(sim + (size_t)(rowbase + chunk * 32 + row) * N_DET
                                     + colbase) + slot;
            __builtin_nontemporal_store(v, sp);
        }

        // 3) top-2 scan: lane -> (row = l&31, col-half = l>>5), 32 cols each
        {
            const int srow = l31;
            const int cofs = half * 32;
            float m1 = -3.0e38f, m2 = -3.0e38f;
            int   i1 = 0, i2 = 0;
            #pragma unroll
            for (int q = 0; q < 8; ++q) {
                f32x4 v = *(const f32x4*)&sm[w][srow][cofs + q * 4];
                float vv[4] = {v.x, v.y, v.z, v.w};
                #pragma unroll
                for (int e = 0; e < 4; ++e) {
                    int c = cofs + q * 4 + e;
                    bool gt1 = vv[e] > m1;
                    bool gt2 = vv[e] > m2;
                    m2 = gt1 ? m1 : (gt2 ? vv[e] : m2);
                    i2 = gt1 ? i1 : (gt2 ? c : i2);
                    m1 = gt1 ? vv[e] : m1;
                    i1 = gt1 ? c : i1;
                }
            }
            // merge halves (partner lane^32 holds the other 32 cols).
            // For lanes<32: own cols < partner cols; strict-> keeps first occurrence.
            float bm1 = __shfl_xor(m1, 32, 64);
            float bm2 = __shfl_xor(m2, 32, 64);
            int   bi1 = __shfl_xor(i1, 32, 64);
            int   bi2 = __shfl_xor(i2, 32, 64);
            float M1, M2; int I1, I2;
            if (bm1 > m1) {
                M1 = bm1; I1 = bi1;
                bool t = bm2 > m1;
                M2 = t ? bm2 : m1; I2 = t ? bi2 : i1;
            } else {
                M1 = m1; I1 = i1;
                bool t = bm1 > m2;
                M2 = t ? bm1 : m2; I2 = t ? bi1 : i2;
            }
            if (l < 32) {
                int row = rowbase + chunk * 32 + srow;
                candbuf[(size_t)row * 128 + cb] =
                    ((unsigned)(colbase + I1) << 16) | (unsigned)(colbase + I2);
            }
        }
        // chunk1's LDS writes are ordered after chunk0's reads (in-order per-wave DS)
    }
}

// ---------------- K3: exact rescue of ALL 256 candidates + fused claim --------------
// One wave per row. 8 chunks of 32 candidate rows staged COALESCED into LDS
// (16 lanes cover one 256B row), then each lane runs the EXACT r7 sequential
// fmaf chain (frozen decision-numerics invariant) on its candidate from LDS.
__global__ __launch_bounds__(256) void k_rescue(
    const float* __restrict__ ef, const unsigned* __restrict__ candbuf,
    u64* __restrict__ rowkey, u64* __restrict__ winner, unsigned uthr)
{
    __shared__ float sm[4][32][65];   // 33 KB, per-wave chunk buffer
    const int w   = threadIdx.x >> 6;
    const int l   = threadIdx.x & 63;
    const int row = blockIdx.x * 4 + w;
    const float* et1f = ef + (size_t)N_DET * 64;
    const unsigned* cbp = candbuf + (size_t)row * 128;

    // q in registers (identical to r7)
    float4 q[16];
    const float4* qp = (const float4*)(ef + (size_t)row * 64);
    #pragma unroll
    for (int i = 0; i < 16; ++i) q[i] = qp[i];

    u64 best = 0ull;
    for (int ch = 0; ch < 8; ++ch) {
        // stage candidate rows j = ch*32 .. ch*32+31, coalesced:
        // instr s: lanes cover 4 rows x 16 segments of 16B
        #pragma unroll
        for (int s = 0; s < 8; ++s) {
            int f   = s * 64 + l;            // 0..511
            int r   = f >> 4;                // row-in-chunk 0..31
            int seg = f & 15;                // 16B segment
            unsigned cw = cbp[ch * 16 + (r >> 1)];
            int c = (r & 1) ? (int)(cw & 0xffffu) : (int)(cw >> 16);
            f32x4 v = *(const f32x4*)(et1f + (size_t)c * 64 + seg * 4);
            *(f32x4*)&sm[w][r][seg * 4] = v;
        }
        // per-wave in-order DS: reads below see this wave's writes above

        // lane l (and its mirror l+32) computes candidate j = ch*32 + (l&31)
        const int r = l & 31;
        unsigned cw = cbp[ch * 16 + (r >> 1)];
        int c = (r & 1) ? (int)(cw & 0xffffu) : (int)(cw >> 16);
        float d = 0.0f;
        #pragma unroll
        for (int i = 0; i < 16; ++i) {
            f32x4 v = *(const f32x4*)&sm[w][r][i * 4];
            d = fmaf(q[i].x, v.x, d);
            d = fmaf(q[i].y, v.y, d);
            d = fmaf(q[i].z, v.z, d);
            d = fmaf(q[i].w, v.w, d);
        }
        u64 k = ((u64)fmap(d) << 32) | (unsigned)~(unsigned)c;
        best = umax64(best, k);
        // next chunk's staging writes are ordered after these reads (in-order DS)
    }
    #pragma unroll
    for (int m = 1; m < 64; m <<= 1)
        best = umax64(best, __shfl_xor(best, m, 64));
    if (l == 0) {
        rowkey[row] = best;
        unsigned u = (unsigned)(best >> 32);
        if (u > uthr) {
            unsigned col = ~(unsigned)best;
            u64 claim = ((u64)u << 32) | (~(unsigned)row);
            atomicMax(&winner[col], claim);
        }
    }
}

// ---------------- K0: zero winner ----------------
__global__ void k_init(u64* __restrict__ p) {
    p[blockIdx.x * 256 + threadIdx.x] = 0ull;
}

// ---------------- K4: resolve matches ----------------
__global__ void k_match(const u64* __restrict__ rowkey,
                        const u64* __restrict__ winner,
                        float* __restrict__ out, unsigned uthr) {
    int i = blockIdx.x * 256 + threadIdx.x;
    if (i >= N_DET) return;
    u64 k = rowkey[i];
    unsigned u = (unsigned)(k >> 32);
    float m = -1.0f;
    if (u > uthr) {
        unsigned col = ~(unsigned)k;
        u64 claim = ((u64)u << 32) | (~(unsigned)i);
        if (winner[col] == claim) m = (float)col;
    }
    out[i] = m;
}

extern "C" void kernel_launch(void* const* d_in, const int* in_sizes, int n_in,
                              void* d_out, int out_size, void* d_ws, size_t ws_size,
                              hipStream_t stream) {
    const float* dt  = (const float*)d_in[0];
    const float* dt1 = (const float*)d_in[1];
    const float* W1  = (const float*)d_in[2];
    const float* b1  = (const float*)d_in[3];
    const float* W2  = (const float*)d_in[4];
    const float* b2  = (const float*)d_in[5];

    float* out = (float*)d_out;            // [0:8192) matches (float), then sim row-major
    float* sim = out + N_DET;

    char* ws = (char*)d_ws;
    float*    ef      = (float*)ws;                                   // 2N*64 f32 = 4 MB
    ushort_t* Phi     = (ushort_t*)(ws + (4u << 20));                 // 2 MB packed
    ushort_t* Plo     = (ushort_t*)(ws + (6u << 20));                 // 2 MB packed
    unsigned* candbuf = (unsigned*)(ws + (8u << 20));                 // 8192*128 u32 = 4 MB
    u64*      rowkey  = (u64*)(ws + (12u << 20));                     // 64 KB
    u64*      winner  = rowkey + N_DET;                               // 64 KB

    unsigned uthr;
    { union { float f; unsigned u; } c; c.f = 0.3f; uthr = c.u | 0x80000000u; }

    k_embed<<<(2 * N_DET) / 4, 256, 0, stream>>>(dt, dt1, W1, b1, W2, b2, ef, Phi, Plo);
    k_init<<<N_DET / 256, 256, 0, stream>>>(winner);

    k_sim_mfma<<<4096, 256, 0, stream>>>(Phi, Plo, sim, candbuf);

    k_rescue<<<N_DET / 4, 256, 0, stream>>>(ef, candbuf, rowkey, winner, uthr);
    k_match<<<N_DET / 256, 256, 0, stream>>>(rowkey, winner, out, uthr);
}